// Round 3
// baseline (78.575 us; speedup 1.0000x reference)
//
#include <hip/hip_runtime.h>
#include <hip/hip_fp16.h>
#include <math.h>

#define N_GENES 20000
#define UNITS   10000
#define DEG     32
#define BATCH   128

// Kernel 1: featT[g][b] = (half)|feature[b][g]| -- 32x32 LDS tile, fused abs+cvt.
// featT rows are 256 B (128 x half), batch-contiguous -> gather loads coalesce.
__global__ __launch_bounds__(256) void transpose_abs_f16_kernel(
    const float* __restrict__ in, __half* __restrict__ out)
{
    __shared__ float tile[32][33];
    const int g0 = blockIdx.x * 32;
    const int b0 = blockIdx.y * 32;
    const int tx = threadIdx.x;   // 0..31
    const int ty = threadIdx.y;   // 0..7
#pragma unroll
    for (int i = 0; i < 32; i += 8)
        tile[ty + i][tx] = fabsf(in[(size_t)(b0 + ty + i) * N_GENES + (g0 + tx)]);
    __syncthreads();
#pragma unroll
    for (int i = 0; i < 32; i += 8)
        out[(size_t)(g0 + ty + i) * BATCH + (b0 + tx)] = __float2half(tile[tx][ty + i]);
}

// Kernel 2 (v4): 16 units/block, 625 blocks, 4 waves.
// Quarter-wave (16 lanes) per unit: lane loads dwordx4 (16 B = 8 batches) of the
// 256 B gene row. Each lane accumulates 8 complete batch-sums for its unit over
// all 32 neighbors -- no shuffles, no inter-pass vmcnt drains (max load MLP).
// Load transactions are mandatory (640K full lines, 100% consumed).
// Stores: LDS transpose -> float4 stores with 16 consecutive units per 64 B run
// (4 lanes/run) -> ~160K store transactions vs 640K scattered before.
__global__ __launch_bounds__(256) void gather_unit_v4(
    const uint4* __restrict__ featT,     // [N_GENES][16] uint4 = [N_GENES][128] half
    const int*   __restrict__ ppi,
    const float* __restrict__ kernelw,
    const float* __restrict__ bias,
    float*       __restrict__ out)
{
    __shared__ int   idx[16 * DEG];      // 512 indices
    __shared__ float outs[BATCH][20];    // [b][unit], pad 16->20 (bank spread, 16B-align)
    const int tid = threadIdx.x;
    const int u0  = blockIdx.x * 16;

    idx[tid]       = ppi[(size_t)u0 * DEG + tid];
    idx[tid + 256] = ppi[(size_t)u0 * DEG + tid + 256];
    __syncthreads();

    const int lane = tid & 63;
    const int w    = tid >> 6;           // 0..3
    const int ul   = w * 4 + (lane >> 4);// local unit 0..15
    const int bq   = lane & 15;          // which 16 B slice of the row
    const int* myidx = idx + ul * DEG;

    float acc0 = 0.f, acc1 = 0.f, acc2 = 0.f, acc3 = 0.f;
    float acc4 = 0.f, acc5 = 0.f, acc6 = 0.f, acc7 = 0.f;

#pragma unroll 8
    for (int d = 0; d < DEG; ++d) {
        const int g = myidx[d];                          // LDS broadcast
        const uint4 raw = featT[(size_t)g * 16 + bq];    // global_load_dwordx4
        const float2 f0 = __half22float2(*reinterpret_cast<const __half2*>(&raw.x));
        const float2 f1 = __half22float2(*reinterpret_cast<const __half2*>(&raw.y));
        const float2 f2 = __half22float2(*reinterpret_cast<const __half2*>(&raw.z));
        const float2 f3 = __half22float2(*reinterpret_cast<const __half2*>(&raw.w));
        acc0 += f0.x; acc1 += f0.y; acc2 += f1.x; acc3 += f1.y;
        acc4 += f2.x; acc5 += f2.y; acc6 += f3.x; acc7 += f3.y;
    }

    const int u  = u0 + ul;
    const float kk = kernelw[u];
    const float cc = bias[u];
    const int bb = bq * 8;               // this lane's batch base

    // tanh(h) = 1 - 2/(exp(2h)+1)
    float a[8] = {acc0, acc1, acc2, acc3, acc4, acc5, acc6, acc7};
#pragma unroll
    for (int j = 0; j < 8; ++j) {
        const float h = a[j] * kk + cc;
        outs[bb + j][ul] = 1.f - 2.f / (__expf(2.f * h) + 1.f);
    }
    __syncthreads();

    // Coalesced store: thread -> (uq = tid&3 : float4 of units, brow = tid>>2).
    // Per b: 4 lanes x 16 B = 64 B contiguous run of consecutive units.
    const int uq   = tid & 3;
    const int brow = tid >> 2;           // 0..63
#pragma unroll
    for (int p = 0; p < 2; ++p) {
        const int b = p * 64 + brow;
        const float4 v = *reinterpret_cast<const float4*>(&outs[b][uq * 4]);
        // address: b*40000 + (u0 + uq*4)*4 bytes; u0%16==0 -> 16 B aligned
        *reinterpret_cast<float4*>(out + (size_t)b * UNITS + u0 + uq * 4) = v;
    }
}

extern "C" void kernel_launch(void* const* d_in, const int* in_sizes, int n_in,
                              void* d_out, int out_size, void* d_ws, size_t ws_size,
                              hipStream_t stream) {
    const float* feature = (const float*)d_in[0];
    const int*   ppi     = (const int*)d_in[1];
    const float* kernelw = (const float*)d_in[2];
    const float* bias    = (const float*)d_in[3];
    float* out   = (float*)d_out;
    __half* featT = (__half*)d_ws;                 // 20000*128*2 = 5.12 MB

    dim3 g1(N_GENES / 32, BATCH / 32);
    dim3 b1(32, 8);
    transpose_abs_f16_kernel<<<g1, b1, 0, stream>>>(feature, featT);

    gather_unit_v4<<<UNITS / 16, 256, 0, stream>>>(
        (const uint4*)featT, ppi, kernelw, bias, out);
}